// Round 4
// baseline (212.243 us; speedup 1.0000x reference)
//
#include <hip/hip_runtime.h>

#define DEVI __device__ __forceinline__

typedef __attribute__((ext_vector_type(8)))  short s16x8;
typedef __attribute__((ext_vector_type(4)))  short s16x4;
typedef __attribute__((ext_vector_type(4)))  float f32x4;
typedef __attribute__((ext_vector_type(16))) float f32x16;
typedef __attribute__((ext_vector_type(2)))  unsigned u32x2;
typedef __attribute__((ext_vector_type(4)))  unsigned u32x4;

// float -> bf16 (RNE)
DEVI short f2bf(float f) {
  unsigned u = __builtin_bit_cast(unsigned, f);
  u = u + 0x7fffu + ((u >> 16) & 1u);
  return (short)(u >> 16);
}
// two floats -> packed bf16 pair (RNE, HW op)
DEVI unsigned cvtpk(float lo, float hi) {
  unsigned r;
  asm("v_cvt_pk_bf16_f32 %0, %1, %2" : "=v"(r) : "v"(lo), "v"(hi));
  return r;
}

constexpr int TT = 512;
constexpr int CC = 64;
constexpr float SCLQ = 0.18033688011112042f;  // log2(e)/8, folded into Q

// Phase-overlaid LDS. p1 (qkv): 66.0 KB. p2 (attn+out): 123.9 KB.
union SMem {
  struct {
    short lq[130 * 64];
    short lk[130 * 64];
    short lv[128 * 64];
    short lvT[64 * 128];
  } p1;
  struct {
    short Kl[4 * 512 * 16];   // frag-major per head
    short Pl[8][2][1280];     // per-wave double-buffered P tile (stride 40)
    float Sums[8][32];
    short la[128 * 64];       // attention output, XOR-swizzled rows
  } p2;
};

// device-wide barrier; cnt memset to 0 each launch; 256 blocks, 1/CU.
DEVI void grid_barrier(unsigned* c) {
  __threadfence();            // release: make prior global writes device-visible
  __syncthreads();
  if (threadIdx.x == 0) {
    __hip_atomic_fetch_add(c, 1u, __ATOMIC_ACQ_REL, __HIP_MEMORY_SCOPE_AGENT);
    while (__hip_atomic_load(c, __ATOMIC_ACQUIRE, __HIP_MEMORY_SCOPE_AGENT) < 256u)
      __builtin_amdgcn_s_sleep(2);
  }
  __syncthreads();
  __threadfence();            // acquire: invalidate stale cache lines
}

__global__ __launch_bounds__(512, 1) void k_fused(
    const float* __restrict__ values, const float* __restrict__ keys,
    const float* __restrict__ query,
    const float* __restrict__ Wq, const float* __restrict__ bq,
    const float* __restrict__ Wk, const float* __restrict__ bk,
    const float* __restrict__ Wv, const float* __restrict__ Wf,
    const float* __restrict__ bfv,
    short* __restrict__ wsw, short* __restrict__ qg, short* __restrict__ kg,
    short* __restrict__ vgT, unsigned* __restrict__ cnt,
    float* __restrict__ out) {
  __shared__ SMem sm;
  const int tid = threadIdx.x;
  const int idx = blockIdx.x;
  // all 4 qq-blocks of a bn on the same XCD (blockIdx % 8 ~ XCD)
  const int xcd = idx & 7, slot = idx >> 3;
  const int bn = xcd * 8 + (slot >> 2), qq = slot & 3;
  const int t0 = qq * 128;
  const size_t xbase = (size_t)bn * TT * CC;
  const int lane = tid & 63, w = tid >> 6;
  const int r = lane & 31, hl = lane >> 5;
  const int d = lane & 15, g = lane >> 4;

  // ========== phase 1a: weight repack (1/256 each) + stage input tile ======
  if (tid < 128) {
    int i = idx * 128 + tid;  // [0, 32768)
    short v; int dsti;
    if (i < 12288)       { int kk = i >> 12, rem = i & 4095; dsti = (kk << 12) + rem;        v = f2bf(Wq[rem * 3 + kk]); }
    else if (i < 24576)  { int j = i - 12288; int kk = j >> 12, rem = j & 4095; dsti = 12288 + (kk << 12) + rem; v = f2bf(Wk[rem * 3 + kk]); }
    else if (i < 28672)  { int j = i - 24576; dsti = 24576 + j; v = f2bf(Wv[j]); }
    else                 { int j = i - 28672; dsti = 28672 + j; v = f2bf(Wf[j]); }
    wsw[dsti] = v;
  }
  for (int s = tid; s < 130 * 8; s += 512) {
    int row = s >> 3, c8 = s & 7;
    int t = t0 - 2 + row;
    u32x4 rq, rk;
    if (t >= 0) {
      const float4 qa = *(const float4*)(query + xbase + (size_t)t * 64 + c8 * 8);
      const float4 qb = *(const float4*)(query + xbase + (size_t)t * 64 + c8 * 8 + 4);
      const float4 ka = *(const float4*)(keys + xbase + (size_t)t * 64 + c8 * 8);
      const float4 kb = *(const float4*)(keys + xbase + (size_t)t * 64 + c8 * 8 + 4);
      rq[0] = cvtpk(qa.x, qa.y); rq[1] = cvtpk(qa.z, qa.w);
      rq[2] = cvtpk(qb.x, qb.y); rq[3] = cvtpk(qb.z, qb.w);
      rk[0] = cvtpk(ka.x, ka.y); rk[1] = cvtpk(ka.z, ka.w);
      rk[2] = cvtpk(kb.x, kb.y); rk[3] = cvtpk(kb.z, kb.w);
    } else {
      rq = (u32x4)(0u); rk = (u32x4)(0u);
    }
    int byte = row * 128 + ((c8 * 16) ^ ((row & 7) << 4));
    *(u32x4*)((char*)sm.p1.lq + byte) = rq;
    *(u32x4*)((char*)sm.p1.lk + byte) = rk;
  }
  for (int s = tid; s < 128 * 8; s += 512) {
    int row = s >> 3, c8 = s & 7;
    const float4 va = *(const float4*)(values + xbase + (size_t)(t0 + row) * 64 + c8 * 8);
    const float4 vb = *(const float4*)(values + xbase + (size_t)(t0 + row) * 64 + c8 * 8 + 4);
    u32x4 rv;
    rv[0] = cvtpk(va.x, va.y); rv[1] = cvtpk(va.z, va.w);
    rv[2] = cvtpk(vb.x, vb.y); rv[3] = cvtpk(vb.z, vb.w);
    int byte = row * 128 + ((c8 * 16) ^ ((row & 7) << 4));
    *(u32x4*)((char*)sm.p1.lv + byte) = rv;
  }

  grid_barrier(cnt + 0);   // weights visible everywhere; LDS staged

  // ========== phase 1b: QKV conv-GEMMs =====================================
  {
    const short* wqb = wsw;            // [3][64][64]
    const short* wkb = wsw + 12288;    // [3][64][64]
    const short* wvb = wsw + 24576;    // [64][64]
    for (int job = w; job < 24; job += 8) {
      int tsr = job >> 3, tj = job & 7, mt = tj >> 1, nt = tj & 1;
      f32x16 acc;
#pragma unroll
      for (int i = 0; i < 16; ++i) acc[i] = 0.f;

      if (tsr < 2) {
        const short* lsrc = tsr ? sm.p1.lk : sm.p1.lq;
        const short* wb = tsr ? wkb : wqb;
#pragma unroll
        for (int kk = 0; kk < 3; ++kk) {
#pragma unroll
          for (int c4 = 0; c4 < 4; ++c4) {
            int lrow = mt * 32 + r + kk;
            int abyte = lrow * 128 + (((c4 * 16 + hl * 8) * 2) ^ ((lrow & 7) << 4));
            s16x8 af = *(const s16x8*)((const char*)lsrc + abyte);
            s16x8 bfr = *(const s16x8*)(wb + kk * 4096 + (nt * 32 + r) * 64 + c4 * 16 + hl * 8);
            acc = __builtin_amdgcn_mfma_f32_32x32x16_bf16(af, bfr, acc, 0, 0, 0);
          }
        }
      } else {
#pragma unroll
        for (int c4 = 0; c4 < 4; ++c4) {
          int lrow = mt * 32 + r;
          int abyte = lrow * 128 + (((c4 * 16 + hl * 8) * 2) ^ ((lrow & 7) << 4));
          s16x8 af = *(const s16x8*)((const char*)sm.p1.lv + abyte);
          s16x8 bfr = *(const s16x8*)(wvb + (nt * 32 + r) * 64 + c4 * 16 + hl * 8);
          acc = __builtin_amdgcn_mfma_f32_32x32x16_bf16(af, bfr, acc, 0, 0, 0);
        }
      }
      int co = nt * 32 + r;
      if (tsr == 2) {
#pragma unroll
        for (int g2 = 0; g2 < 4; ++g2) {
          int tl = mt * 32 + g2 * 8 + hl * 4;
          u32x2 pk;
          pk[0] = cvtpk(acc[g2 * 4 + 0], acc[g2 * 4 + 1]);
          pk[1] = cvtpk(acc[g2 * 4 + 2], acc[g2 * 4 + 3]);
          *(u32x2*)(sm.p1.lvT + co * 128 + (tl ^ ((co & 15) << 2))) = pk;
        }
      } else {
        float bias = tsr ? bk[co] : bq[co];
        float scl = tsr ? 1.f : SCLQ;
        short* dst = tsr ? kg : qg;
#pragma unroll
        for (int reg = 0; reg < 16; ++reg) {
          int trow = mt * 32 + (reg & 3) + 8 * (reg >> 2) + 4 * hl;
          dst[((size_t)bn * TT + (t0 + trow)) * 64 + co] = f2bf((acc[reg] + bias) * scl);
        }
      }
    }
    __syncthreads();
    // coalesced copy-out: vgT[bn][co][t0 + t]
#pragma unroll
    for (int i = 0; i < 4; ++i) {
      int chunk = tid + 512 * i;          // 2048 chunks of 4 shorts
      int co = chunk >> 5, tc = chunk & 31;
      s16x4 v4 = *(const s16x4*)(sm.p1.lvT + co * 128 + ((tc * 4) ^ ((co & 15) << 2)));
      *(s16x4*)(vgT + ((size_t)bn * 64 + co) * TT + t0 + tc * 4) = v4;
    }
  }

  grid_barrier(cnt + 1);   // qg/kg/vgT visible everywhere

  // ========== phase 2: attention (16 tasks = 4 heads x 4 sub-tiles) ========
  // stage K slice (512 x 64 -> per-head fragment-major)
  for (int s = tid; s < 4096; s += 512) {
    int row = s >> 3, c8 = s & 7;
    int hh = c8 >> 1, half = c8 & 1;
    s16x8 kv = *(const s16x8*)(kg + ((size_t)bn * TT + row) * CC + c8 * 8);
    *(s16x8*)(sm.p2.Kl + hh * 8192 + (row >> 5) * 512 + (row & 31) * 8 + half * 256) = kv;
  }
  __syncthreads();

  f32x16 z;
#pragma unroll
  for (int i = 0; i < 16; ++i) z[i] = 0.f;

  for (int task = w; task < 16; task += 8) {
    int h = task >> 2, mtl = task & 3;
    int mt = qq * 4 + mtl;
    s16x8 qf = *(const s16x8*)(qg + ((size_t)bn * TT + mt * 32 + r) * CC + h * 16 + hl * 8);
    const short* vb = vgT + ((size_t)bn * 64 + h * 16 + d) * TT + g * 8;

    float sm0 = 0.f, sm1 = 0.f, sm2 = 0.f, sm3 = 0.f;
    f32x4 o1, o2;
#pragma unroll
    for (int i = 0; i < 4; ++i) { o1[i] = 0.f; o2[i] = 0.f; }

#pragma unroll
    for (int nt = 0; nt < 16; ++nt) {
      s16x8 kf = *(const s16x8*)(sm.p2.Kl + h * 8192 + nt * 512 + lane * 8);
      s16x8 vf = *(const s16x8*)(vb + nt * 32);
      f32x16 s = __builtin_amdgcn_mfma_f32_32x32x16_bf16(kf, qf, z, 0, 0, 0);
      short* plb = sm.p2.Pl[w][nt & 1];
#pragma unroll
      for (int g2 = 0; g2 < 4; ++g2) {
        float p0 = exp2f(s[4 * g2 + 0]);
        float p1 = exp2f(s[4 * g2 + 1]);
        float p2 = exp2f(s[4 * g2 + 2]);
        float p3 = exp2f(s[4 * g2 + 3]);
        sm0 += p0; sm1 += p1; sm2 += p2; sm3 += p3;
        u32x2 pk;
        pk[0] = cvtpk(p0, p1);
        pk[1] = cvtpk(p2, p3);
        *(u32x2*)(plb + r * 40 + g2 * 8 + hl * 4) = pk;
      }
      s16x8 pa = *(const s16x8*)(plb + d * 40 + g * 8);
      s16x8 pb = *(const s16x8*)(plb + (16 + d) * 40 + g * 8);
      o1 = __builtin_amdgcn_mfma_f32_16x16x32_bf16(pa, vf, o1, 0, 0, 0);
      o2 = __builtin_amdgcn_mfma_f32_16x16x32_bf16(pb, vf, o2, 0, 0, 0);
    }
    float sum = (sm0 + sm1) + (sm2 + sm3);
    sum += __shfl_xor(sum, 32);
    sm.p2.Sums[w][r] = sum;
#pragma unroll
    for (int reg = 0; reg < 4; ++reg) {
      float i1 = __builtin_amdgcn_rcpf(sm.p2.Sums[w][g * 4 + reg]);
      float i2 = __builtin_amdgcn_rcpf(sm.p2.Sums[w][16 + g * 4 + reg]);
      int row1 = mtl * 32 + g * 4 + reg, row2 = row1 + 16;
      int col = h * 16 + d;
      int cb = (col >> 3) * 16, ci = (col & 7) * 2;
      *(short*)((char*)sm.p2.la + row1 * 128 + (cb ^ ((row1 & 7) << 4)) + ci) = f2bf(o1[reg] * i1);
      *(short*)((char*)sm.p2.la + row2 * 128 + (cb ^ ((row2 & 7) << 4)) + ci) = f2bf(o2[reg] * i2);
    }
  }
  __syncthreads();

  // ========== phase 3: out = A @ Wf^T + bf (fp32) ==========================
  {
    int mt2 = w >> 1, nt = w & 1;  // 8 jobs, 1 per wave
    f32x16 acc;
#pragma unroll
    for (int i = 0; i < 16; ++i) acc[i] = 0.f;
#pragma unroll
    for (int c4 = 0; c4 < 4; ++c4) {
      int lrow = mt2 * 32 + r;
      int abyte = lrow * 128 + (((c4 * 16 + hl * 8) * 2) ^ ((lrow & 7) << 4));
      s16x8 af = *(const s16x8*)((const char*)sm.p2.la + abyte);
      s16x8 bfr = *(const s16x8*)(wsw + 28672 + (nt * 32 + r) * 64 + c4 * 16 + hl * 8);
      acc = __builtin_amdgcn_mfma_f32_32x32x16_bf16(af, bfr, acc, 0, 0, 0);
    }
    int co = nt * 32 + r;
    float bias = bfv[co];
#pragma unroll
    for (int reg = 0; reg < 16; ++reg) {
      int trow = mt2 * 32 + (reg & 3) + 8 * (reg >> 2) + 4 * hl;
      out[((size_t)bn * TT + t0 + trow) * CC + co] = acc[reg] + bias;
    }
  }
}

// ---------------------------------------------------------------------------
extern "C" void kernel_launch(void* const* d_in, const int* in_sizes, int n_in,
                              void* d_out, int out_size, void* d_ws, size_t ws_size,
                              hipStream_t stream) {
  const float* values = (const float*)d_in[0];
  const float* keys = (const float*)d_in[1];
  const float* query = (const float*)d_in[2];
  const float* Wq = (const float*)d_in[3];
  const float* bq = (const float*)d_in[4];
  const float* Wk = (const float*)d_in[5];
  const float* bk = (const float*)d_in[6];
  const float* Wv = (const float*)d_in[7];
  const float* Wf = (const float*)d_in[8];
  const float* bfv = (const float*)d_in[9];
  float* out = (float*)d_out;

  char* ws = (char*)d_ws;
  short* wsw = (short*)ws;                              // 64 KiB weights (bf16)
  short* qg = (short*)(ws + (1 << 16));                 // 4 MiB
  short* kg = (short*)(ws + (1 << 16) + (1 << 22));     // 4 MiB
  short* vgT = (short*)(ws + (1 << 16) + 2 * (1 << 22));// 4 MiB
  unsigned* cnt = (unsigned*)(ws + (1 << 24));          // barrier counters

  hipMemsetAsync(cnt, 0, 256, stream);
  hipLaunchKernelGGL(k_fused, dim3(256), dim3(512), 0, stream,
                     values, keys, query, Wq, bq, Wk, bk, Wv, Wf, bfv,
                     wsw, qg, kg, vgT, cnt, out);
}

// Round 5
// 55.681 us; speedup vs baseline: 3.8118x; 3.8118x over previous
//
#include <hip/hip_runtime.h>

#define DEVI __device__ __forceinline__

typedef __attribute__((ext_vector_type(8)))  short s16x8;
typedef __attribute__((ext_vector_type(4)))  short s16x4;
typedef __attribute__((ext_vector_type(4)))  float f32x4;
typedef __attribute__((ext_vector_type(16))) float f32x16;
typedef __attribute__((ext_vector_type(2)))  unsigned u32x2;
typedef __attribute__((ext_vector_type(4)))  unsigned u32x4;

// float -> bf16 (RNE), bit pattern as short
DEVI short f2bf(float f) {
  unsigned u = __builtin_bit_cast(unsigned, f);
  u = u + 0x7fffu + ((u >> 16) & 1u);
  return (short)(u >> 16);
}

// two floats -> packed bf16 pair via HW cvt (RNE)
DEVI unsigned cvtpk(float lo, float hi) {
  unsigned r;
  asm("v_cvt_pk_bf16_f32 %0, %1, %2" : "=v"(r) : "v"(lo), "v"(hi));
  return r;
}

constexpr int TT = 512;
constexpr int CC = 64;
constexpr float SCLQ = 0.18033688011112042f;  // log2(e)/8, folded into Q

// ---------------------------------------------------------------------------
// Kernel 0: weight repack fp32 -> bf16.  WqB[kk][co][ci] = Wq[co][ci][kk]
// ---------------------------------------------------------------------------
__global__ __launch_bounds__(256) void k_prep(const float* __restrict__ Wq,
                                              const float* __restrict__ Wk,
                                              const float* __restrict__ Wv,
                                              const float* __restrict__ Wf,
                                              short* __restrict__ wsw) {
  int i = blockIdx.x * 256 + threadIdx.x;
  const int total = 12288 + 12288 + 4096 + 4096;
  if (i >= total) return;
  if (i < 12288) {
    int kk = i >> 12, rem = i & 4095;
    wsw[(kk << 12) + rem] = f2bf(Wq[rem * 3 + kk]);
  } else if (i < 24576) {
    int j = i - 12288;
    int kk = j >> 12, rem = j & 4095;
    wsw[12288 + (kk << 12) + rem] = f2bf(Wk[rem * 3 + kk]);
  } else if (i < 28672) {
    int j = i - 24576;
    wsw[24576 + j] = f2bf(Wv[j]);
  } else {
    int j = i - 28672;
    wsw[28672 + j] = f2bf(Wf[j]);
  }
}

// ---------------------------------------------------------------------------
// Kernel 1: Q/K causal conv (3 shifted GEMMs) + V 1x1 conv via
// mfma_f32_32x32x16_bf16.  Q is pre-scaled by log2(e)/8.  V is written
// TRANSPOSED: vgT[bn][c][t]  (via LDS transpose + coalesced copy-out).
// ---------------------------------------------------------------------------
__global__ __launch_bounds__(256) void k_qkv(const float* __restrict__ values,
                                             const float* __restrict__ keys,
                                             const float* __restrict__ query,
                                             const float* __restrict__ bq,
                                             const float* __restrict__ bk,
                                             const short* __restrict__ wsw,
                                             short* __restrict__ qg,
                                             short* __restrict__ kg,
                                             short* __restrict__ vgT) {
  __shared__ __align__(16) short lq[130 * 64];
  __shared__ __align__(16) short lk[130 * 64];
  __shared__ __align__(16) short lv[128 * 64];
  __shared__ __align__(16) short lvT[64 * 128];  // [co][t_local], XOR swizzled
  const int tid = threadIdx.x;
  const int bn = blockIdx.x >> 2, ttile = blockIdx.x & 3;
  const int t0 = ttile * 128;
  const size_t xbase = (size_t)bn * TT * CC;

  // stage query/keys rows [t0-2, t0+128)  (zeros for t<0) — float4 loads
  for (int s = tid; s < 130 * 8; s += 256) {
    int row = s >> 3, c8 = s & 7;
    int t = t0 - 2 + row;
    s16x8 rq, rk;
    if (t >= 0) {
      const float4 qa = *(const float4*)(query + xbase + (size_t)t * 64 + c8 * 8);
      const float4 qb = *(const float4*)(query + xbase + (size_t)t * 64 + c8 * 8 + 4);
      const float4 ka = *(const float4*)(keys + xbase + (size_t)t * 64 + c8 * 8);
      const float4 kb = *(const float4*)(keys + xbase + (size_t)t * 64 + c8 * 8 + 4);
      rq[0] = f2bf(qa.x); rq[1] = f2bf(qa.y); rq[2] = f2bf(qa.z); rq[3] = f2bf(qa.w);
      rq[4] = f2bf(qb.x); rq[5] = f2bf(qb.y); rq[6] = f2bf(qb.z); rq[7] = f2bf(qb.w);
      rk[0] = f2bf(ka.x); rk[1] = f2bf(ka.y); rk[2] = f2bf(ka.z); rk[3] = f2bf(ka.w);
      rk[4] = f2bf(kb.x); rk[5] = f2bf(kb.y); rk[6] = f2bf(kb.z); rk[7] = f2bf(kb.w);
    } else {
#pragma unroll
      for (int j = 0; j < 8; ++j) { rq[j] = 0; rk[j] = 0; }
    }
    int byte = row * 128 + ((c8 * 16) ^ ((row & 7) << 4));
    *(s16x8*)((char*)lq + byte) = rq;
    *(s16x8*)((char*)lk + byte) = rk;
  }
  // stage values rows [t0, t0+128)
  for (int s = tid; s < 128 * 8; s += 256) {
    int row = s >> 3, c8 = s & 7;
    const float4 va = *(const float4*)(values + xbase + (size_t)(t0 + row) * 64 + c8 * 8);
    const float4 vb = *(const float4*)(values + xbase + (size_t)(t0 + row) * 64 + c8 * 8 + 4);
    s16x8 rv;
    rv[0] = f2bf(va.x); rv[1] = f2bf(va.y); rv[2] = f2bf(va.z); rv[3] = f2bf(va.w);
    rv[4] = f2bf(vb.x); rv[5] = f2bf(vb.y); rv[6] = f2bf(vb.z); rv[7] = f2bf(vb.w);
    int byte = row * 128 + ((c8 * 16) ^ ((row & 7) << 4));
    *(s16x8*)((char*)lv + byte) = rv;
  }
  __syncthreads();

  const int lane = tid & 63, w = tid >> 6;
  const int r = lane & 31, hl = lane >> 5;
  const short* wqb = wsw;            // [3][64][64]
  const short* wkb = wsw + 12288;    // [3][64][64]
  const short* wvb = wsw + 24576;    // [64][64]

  // 24 tiles: tensor(3: Q,K,V) x mt(4) x nt(2); wave-strided
  for (int job = w; job < 24; job += 4) {
    int tsr = job >> 3, tj = job & 7, mt = tj >> 1, nt = tj & 1;
    f32x16 acc;
#pragma unroll
    for (int i = 0; i < 16; ++i) acc[i] = 0.f;

    if (tsr < 2) {
      const short* lsrc = tsr ? lk : lq;
      const short* wb = tsr ? wkb : wqb;
#pragma unroll
      for (int kk = 0; kk < 3; ++kk) {
#pragma unroll
        for (int c4 = 0; c4 < 4; ++c4) {
          int lrow = mt * 32 + r + kk;
          int abyte = lrow * 128 + (((c4 * 16 + hl * 8) * 2) ^ ((lrow & 7) << 4));
          s16x8 af = *(const s16x8*)((const char*)lsrc + abyte);
          s16x8 bfr = *(const s16x8*)(wb + kk * 4096 + (nt * 32 + r) * 64 + c4 * 16 + hl * 8);
          acc = __builtin_amdgcn_mfma_f32_32x32x16_bf16(af, bfr, acc, 0, 0, 0);
        }
      }
    } else {
#pragma unroll
      for (int c4 = 0; c4 < 4; ++c4) {
        int lrow = mt * 32 + r;
        int abyte = lrow * 128 + (((c4 * 16 + hl * 8) * 2) ^ ((lrow & 7) << 4));
        s16x8 af = *(const s16x8*)((const char*)lv + abyte);
        s16x8 bfr = *(const s16x8*)(wvb + (nt * 32 + r) * 64 + c4 * 16 + hl * 8);
        acc = __builtin_amdgcn_mfma_f32_32x32x16_bf16(af, bfr, acc, 0, 0, 0);
      }
    }
    int co = nt * 32 + r;
    if (tsr == 2) {
      // V: write to transposed LDS tile (XOR-swizzled, 8B chunks)
#pragma unroll
      for (int g2 = 0; g2 < 4; ++g2) {
        int tl = mt * 32 + g2 * 8 + hl * 4;   // 4 consecutive t
        s16x4 pk;
        pk[0] = f2bf(acc[g2 * 4 + 0]);
        pk[1] = f2bf(acc[g2 * 4 + 1]);
        pk[2] = f2bf(acc[g2 * 4 + 2]);
        pk[3] = f2bf(acc[g2 * 4 + 3]);
        *(s16x4*)(lvT + co * 128 + (tl ^ ((co & 15) << 2))) = pk;
      }
    } else {
      float bias = tsr ? bk[co] : bq[co];
      float scl = tsr ? 1.f : SCLQ;
      short* dst = tsr ? kg : qg;
#pragma unroll
      for (int reg = 0; reg < 16; ++reg) {
        int trow = mt * 32 + (reg & 3) + 8 * (reg >> 2) + 4 * hl;
        dst[((size_t)bn * TT + (t0 + trow)) * 64 + co] = f2bf((acc[reg] + bias) * scl);
      }
    }
  }
  __syncthreads();
  // coalesced copy-out: vgT[bn][co][t0 + t]
#pragma unroll
  for (int i = 0; i < 8; ++i) {
    int chunk = tid + 256 * i;          // 2048 chunks of 4 shorts
    int co = chunk >> 5, tc = chunk & 31;
    s16x4 v4 = *(const s16x4*)(lvT + co * 128 + ((tc * 4) ^ ((co & 15) << 2)));
    *(s16x4*)(vgT + ((size_t)bn * 64 + co) * TT + t0 + tc * 4) = v4;
  }
}

// ---------------------------------------------------------------------------
// Kernel 2: attention.  Grid 1024 = (bn, h, qquarter); 4 waves, 1 mt/wave.
// One-pass no-max softmax (Q pre-scaled).  Swapped QK^T (mfma(K,Q)) leaves
// lane (r,hl) holding q-row r, k = nt*32 + (reg&3)+8*(reg>>2)+4*hl.
// P goes to PV *in registers*: cvt_pk pairs, then v_permlane32_swap_b32
// redistributes dwords into 32x32x16 A-fragments (k = s*16 + hl*8 + j).
// PV = 2x mfma_32x32x16 per nt, single f32x16 accumulator; V B-frags are
// contiguous 16B loads from vgT (cols >=16 discarded duplicates).
// No P LDS buffer at all.
// ---------------------------------------------------------------------------
__global__ __launch_bounds__(256, 4) void k_attn(const short* __restrict__ qg,
                                                 const short* __restrict__ kg,
                                                 const short* __restrict__ vgT,
                                                 short* __restrict__ ag) {
  __shared__ __align__(16) short Kl[512 * 16];   // frag-major: tile nt at nt*512, lane*8
  __shared__ float Sums[4][32];
  const int tid = threadIdx.x;
  // bijective XCD swizzle: all 16 (h,qq) blocks of one bn land on one XCD
  const int b = (blockIdx.x & 7) * 128 + (blockIdx.x >> 3);
  const int bn = b >> 4, h = (b >> 2) & 3, qq = b & 3;
  const int lane = tid & 63, w = tid >> 6;
  const int r = lane & 31, hl = lane >> 5;

  // stage K slice (512 x 16) into fragment-major LDS
  const short* kslice = kg + (size_t)bn * TT * CC + h * 16;
  for (int s = tid; s < 1024; s += 256) {
    int row = s >> 1, hh = s & 1;
    s16x8 kv = *(const s16x8*)(kslice + (size_t)row * CC + hh * 8);
    *(s16x8*)(Kl + (row >> 5) * 512 + (row & 31) * 8 + hh * 256) = kv;
  }

  const int mt = qq * 4 + w;
  s16x8 qf = *(const s16x8*)(qg + ((size_t)bn * TT + mt * 32 + r) * CC + h * 16 + hl * 8);
  // per-lane V channel row (r>=16 duplicates r-16; those output cols discarded)
  const short* vb = vgT + ((size_t)bn * 64 + h * 16 + (r & 15)) * TT;

  __syncthreads();

  f32x16 z;
#pragma unroll
  for (int i = 0; i < 16; ++i) z[i] = 0.f;
  float sm0 = 0.f, sm1 = 0.f, sm2 = 0.f, sm3 = 0.f;
  f32x16 o;
#pragma unroll
  for (int i = 0; i < 16; ++i) o[i] = 0.f;

#pragma unroll
  for (int nt = 0; nt < 16; ++nt) {
    s16x8 kf = *(const s16x8*)(Kl + nt * 512 + lane * 8);
    f32x16 s = __builtin_amdgcn_mfma_f32_32x32x16_bf16(kf, qf, z, 0, 0, 0);
    float p[16];
#pragma unroll
    for (int i = 0; i < 16; ++i) p[i] = exp2f(s[i]);
#pragma unroll
    for (int i = 0; i < 4; ++i) {
      sm0 += p[4 * i + 0]; sm1 += p[4 * i + 1];
      sm2 += p[4 * i + 2]; sm3 += p[4 * i + 3];
    }
    unsigned pk[8];
#pragma unroll
    for (int m = 0; m < 8; ++m) pk[m] = cvtpk(p[2 * m], p[2 * m + 1]);
#pragma unroll
    for (int s2 = 0; s2 < 2; ++s2) {
      unsigned a0 = pk[4 * s2 + 0], b0 = pk[4 * s2 + 2];
      unsigned a1 = pk[4 * s2 + 1], b1 = pk[4 * s2 + 3];
      // exchange vdst.hi <-> vsrc.lo: a -> frag dword (lo-k), b -> (hi-k)
      asm("v_permlane32_swap_b32 %0, %1" : "+v"(a0), "+v"(b0));
      asm("v_permlane32_swap_b32 %0, %1" : "+v"(a1), "+v"(b1));
      u32x4 fw; fw[0] = a0; fw[1] = a1; fw[2] = b0; fw[3] = b1;
      s16x8 fr = __builtin_bit_cast(s16x8, fw);
      s16x8 vf = *(const s16x8*)(vb + nt * 32 + s2 * 16 + hl * 8);
      o = __builtin_amdgcn_mfma_f32_32x32x16_bf16(fr, vf, o, 0, 0, 0);
    }
  }
  float sum = (sm0 + sm1) + (sm2 + sm3);
  sum += __shfl_xor(sum, 32);
  Sums[w][r] = sum;
  if (r < 16) {
#pragma unroll
    for (int reg = 0; reg < 16; ++reg) {
      int qlocal = (reg & 3) + 8 * (reg >> 2) + 4 * hl;
      float inv = __builtin_amdgcn_rcpf(Sums[w][qlocal]);
      int q = mt * 32 + qlocal;
      ag[((size_t)bn * TT + q) * CC + h * 16 + r] = f2bf(o[reg] * inv);
    }
  }
}

// ---------------------------------------------------------------------------
// Kernel 3: final linear out = attn @ Wf^T + bf (fp32 out)
// ---------------------------------------------------------------------------
__global__ __launch_bounds__(256) void k_out(const short* __restrict__ ag,
                                             const short* __restrict__ wfb,
                                             const float* __restrict__ bfv,
                                             float* __restrict__ out) {
  __shared__ __align__(16) short la[128 * 64];
  const int tid = threadIdx.x;
  const int bn = blockIdx.x >> 2, ttile = blockIdx.x & 3;
  const int t0 = ttile * 128;
  for (int s = tid; s < 128 * 8; s += 256) {
    int row = s >> 3, c8 = s & 7;
    s16x8 v = *(const s16x8*)(ag + ((size_t)bn * TT + t0 + row) * 64 + c8 * 8);
    int byte = row * 128 + ((c8 * 16) ^ ((row & 7) << 4));
    *(s16x8*)((char*)la + byte) = v;
  }
  __syncthreads();
  const int lane = tid & 63, w = tid >> 6;
  const int r = lane & 31, hl = lane >> 5;
  for (int job = w; job < 8; job += 4) {
    int mt = job >> 1, nt = job & 1;
    f32x16 acc;
#pragma unroll
    for (int i = 0; i < 16; ++i) acc[i] = 0.f;
#pragma unroll
    for (int c4 = 0; c4 < 4; ++c4) {
      int lrow = mt * 32 + r;
      int abyte = lrow * 128 + (((c4 * 16 + hl * 8) * 2) ^ ((lrow & 7) << 4));
      s16x8 af = *(const s16x8*)((const char*)la + abyte);
      s16x8 bfr = *(const s16x8*)(wfb + (nt * 32 + r) * 64 + c4 * 16 + hl * 8);
      acc = __builtin_amdgcn_mfma_f32_32x32x16_bf16(af, bfr, acc, 0, 0, 0);
    }
    int co = nt * 32 + r;
    float bias = bfv[co];
#pragma unroll
    for (int reg = 0; reg < 16; ++reg) {
      int trow = mt * 32 + (reg & 3) + 8 * (reg >> 2) + 4 * hl;
      out[((size_t)bn * TT + t0 + trow) * 64 + co] = acc[reg] + bias;
    }
  }
}

// ---------------------------------------------------------------------------
extern "C" void kernel_launch(void* const* d_in, const int* in_sizes, int n_in,
                              void* d_out, int out_size, void* d_ws, size_t ws_size,
                              hipStream_t stream) {
  const float* values = (const float*)d_in[0];
  const float* keys = (const float*)d_in[1];
  const float* query = (const float*)d_in[2];
  const float* Wq = (const float*)d_in[3];
  const float* bq = (const float*)d_in[4];
  const float* Wk = (const float*)d_in[5];
  const float* bk = (const float*)d_in[6];
  const float* Wv = (const float*)d_in[7];
  const float* Wf = (const float*)d_in[8];
  const float* bfv = (const float*)d_in[9];
  float* out = (float*)d_out;

  char* ws = (char*)d_ws;
  short* wsw = (short*)ws;                              // 64 KiB weights
  short* qg = (short*)(ws + (1 << 16));                 // 4 MiB each
  short* kg = (short*)(ws + (1 << 16) + (1 << 22));
  short* vgT = (short*)(ws + (1 << 16) + 2 * (1 << 22));
  short* ag = (short*)(ws + (1 << 16) + 3 * (size_t)(1 << 22));

  hipLaunchKernelGGL(k_prep, dim3(128), dim3(256), 0, stream, Wq, Wk, Wv, Wf, wsw);
  hipLaunchKernelGGL(k_qkv, dim3(256), dim3(256), 0, stream,
                     values, keys, query, bq, bk, wsw, qg, kg, vgT);
  hipLaunchKernelGGL(k_attn, dim3(1024), dim3(256), 0, stream, qg, kg, vgT, ag);
  hipLaunchKernelGGL(k_out, dim3(256), dim3(256), 0, stream, ag, wsw + 28672, bfv, out);
}

// Round 9
// 52.188 us; speedup vs baseline: 4.0669x; 1.0669x over previous
//
#include <hip/hip_runtime.h>

#define DEVI __device__ __forceinline__

typedef __attribute__((ext_vector_type(8)))  short s16x8;
typedef __attribute__((ext_vector_type(4)))  short s16x4;
typedef __attribute__((ext_vector_type(4)))  float f32x4;
typedef __attribute__((ext_vector_type(16))) float f32x16;
typedef __attribute__((ext_vector_type(2)))  unsigned u32x2;
typedef __attribute__((ext_vector_type(4)))  unsigned u32x4;

// float -> bf16 (RNE), bit pattern as short
DEVI short f2bf(float f) {
  unsigned u = __builtin_bit_cast(unsigned, f);
  u = u + 0x7fffu + ((u >> 16) & 1u);
  return (short)(u >> 16);
}
// two floats -> packed bf16 pair via HW cvt (RNE)
DEVI unsigned cvtpk(float lo, float hi) {
  unsigned r;
  asm("v_cvt_pk_bf16_f32 %0, %1, %2" : "=v"(r) : "v"(lo), "v"(hi));
  return r;
}

constexpr int TT = 512;
constexpr int CC = 64;
constexpr float SCLQ = 0.18033688011112042f;  // log2(e)/8, folded into Q

// ---------------------------------------------------------------------------
// Kernel 0: weight repack fp32 -> bf16.  WqB[kk][co][ci] = Wq[co][ci][kk]
// ---------------------------------------------------------------------------
__global__ __launch_bounds__(256) void k_prep(const float* __restrict__ Wq,
                                              const float* __restrict__ Wk,
                                              const float* __restrict__ Wv,
                                              const float* __restrict__ Wf,
                                              short* __restrict__ wsw) {
  int i = blockIdx.x * 256 + threadIdx.x;
  const int total = 12288 + 12288 + 4096 + 4096;
  if (i >= total) return;
  if (i < 12288) {
    int kk = i >> 12, rem = i & 4095;
    wsw[(kk << 12) + rem] = f2bf(Wq[rem * 3 + kk]);
  } else if (i < 24576) {
    int j = i - 12288;
    int kk = j >> 12, rem = j & 4095;
    wsw[12288 + (kk << 12) + rem] = f2bf(Wk[rem * 3 + kk]);
  } else if (i < 28672) {
    int j = i - 24576;
    wsw[24576 + j] = f2bf(Wv[j]);
  } else {
    int j = i - 28672;
    wsw[28672 + j] = f2bf(Wf[j]);
  }
}

// ---------------------------------------------------------------------------
// Kernel 1: Q/K causal conv (3 shifted GEMMs) + V 1x1 conv via
// mfma_f32_32x32x16_bf16.  Q pre-scaled by log2(e)/8.  V written transposed
// vgT[bn][c][t] via LDS transpose.  Staging packs bf16 with cvt_pk
// (pattern validated in round 4's passing fused kernel).
// ---------------------------------------------------------------------------
__global__ __launch_bounds__(256) void k_qkv(const float* __restrict__ values,
                                             const float* __restrict__ keys,
                                             const float* __restrict__ query,
                                             const float* __restrict__ bq,
                                             const float* __restrict__ bk,
                                             const short* __restrict__ wsw,
                                             short* __restrict__ qg,
                                             short* __restrict__ kg,
                                             short* __restrict__ vgT) {
  __shared__ __align__(16) short lq[130 * 64];
  __shared__ __align__(16) short lk[130 * 64];
  __shared__ __align__(16) short lv[128 * 64];
  __shared__ __align__(16) short lvT[64 * 128];  // [co][t_local], XOR swizzled
  const int tid = threadIdx.x;
  const int bn = blockIdx.x >> 2, ttile = blockIdx.x & 3;
  const int t0 = ttile * 128;
  const size_t xbase = (size_t)bn * TT * CC;

  // stage query/keys rows [t0-2, t0+128)  (zeros for t<0)
  for (int s = tid; s < 130 * 8; s += 256) {
    int row = s >> 3, c8 = s & 7;
    int t = t0 - 2 + row;
    u32x4 rq, rk;
    if (t >= 0) {
      const float4 qa = *(const float4*)(query + xbase + (size_t)t * 64 + c8 * 8);
      const float4 qb = *(const float4*)(query + xbase + (size_t)t * 64 + c8 * 8 + 4);
      const float4 ka = *(const float4*)(keys + xbase + (size_t)t * 64 + c8 * 8);
      const float4 kb = *(const float4*)(keys + xbase + (size_t)t * 64 + c8 * 8 + 4);
      rq[0] = cvtpk(qa.x, qa.y); rq[1] = cvtpk(qa.z, qa.w);
      rq[2] = cvtpk(qb.x, qb.y); rq[3] = cvtpk(qb.z, qb.w);
      rk[0] = cvtpk(ka.x, ka.y); rk[1] = cvtpk(ka.z, ka.w);
      rk[2] = cvtpk(kb.x, kb.y); rk[3] = cvtpk(kb.z, kb.w);
    } else {
      rq = (u32x4)(0u); rk = (u32x4)(0u);
    }
    int byte = row * 128 + ((c8 * 16) ^ ((row & 7) << 4));
    *(u32x4*)((char*)lq + byte) = rq;
    *(u32x4*)((char*)lk + byte) = rk;
  }
  // stage values rows [t0, t0+128)
  for (int s = tid; s < 128 * 8; s += 256) {
    int row = s >> 3, c8 = s & 7;
    const float4 va = *(const float4*)(values + xbase + (size_t)(t0 + row) * 64 + c8 * 8);
    const float4 vb = *(const float4*)(values + xbase + (size_t)(t0 + row) * 64 + c8 * 8 + 4);
    u32x4 rv;
    rv[0] = cvtpk(va.x, va.y); rv[1] = cvtpk(va.z, va.w);
    rv[2] = cvtpk(vb.x, vb.y); rv[3] = cvtpk(vb.z, vb.w);
    int byte = row * 128 + ((c8 * 16) ^ ((row & 7) << 4));
    *(u32x4*)((char*)lv + byte) = rv;
  }
  __syncthreads();

  const int lane = tid & 63, w = tid >> 6;
  const int r = lane & 31, hl = lane >> 5;
  const short* wqb = wsw;            // [3][64][64]
  const short* wkb = wsw + 12288;    // [3][64][64]
  const short* wvb = wsw + 24576;    // [64][64]

  // 24 tiles: tensor(3: Q,K,V) x mt(4) x nt(2); wave-strided
  for (int job = w; job < 24; job += 4) {
    int tsr = job >> 3, tj = job & 7, mt = tj >> 1, nt = tj & 1;
    f32x16 acc;
#pragma unroll
    for (int i = 0; i < 16; ++i) acc[i] = 0.f;

    if (tsr < 2) {
      const short* lsrc = tsr ? lk : lq;
      const short* wb = tsr ? wkb : wqb;
#pragma unroll
      for (int kk = 0; kk < 3; ++kk) {
#pragma unroll
        for (int c4 = 0; c4 < 4; ++c4) {
          int lrow = mt * 32 + r + kk;
          int abyte = lrow * 128 + (((c4 * 16 + hl * 8) * 2) ^ ((lrow & 7) << 4));
          s16x8 af = *(const s16x8*)((const char*)lsrc + abyte);
          s16x8 bfr = *(const s16x8*)(wb + kk * 4096 + (nt * 32 + r) * 64 + c4 * 16 + hl * 8);
          acc = __builtin_amdgcn_mfma_f32_32x32x16_bf16(af, bfr, acc, 0, 0, 0);
        }
      }
    } else {
#pragma unroll
      for (int c4 = 0; c4 < 4; ++c4) {
        int lrow = mt * 32 + r;
        int abyte = lrow * 128 + (((c4 * 16 + hl * 8) * 2) ^ ((lrow & 7) << 4));
        s16x8 af = *(const s16x8*)((const char*)lv + abyte);
        s16x8 bfr = *(const s16x8*)(wvb + (nt * 32 + r) * 64 + c4 * 16 + hl * 8);
        acc = __builtin_amdgcn_mfma_f32_32x32x16_bf16(af, bfr, acc, 0, 0, 0);
      }
    }
    int co = nt * 32 + r;
    if (tsr == 2) {
#pragma unroll
      for (int g2 = 0; g2 < 4; ++g2) {
        int tl = mt * 32 + g2 * 8 + hl * 4;
        u32x2 pk;
        pk[0] = cvtpk(acc[g2 * 4 + 0], acc[g2 * 4 + 1]);
        pk[1] = cvtpk(acc[g2 * 4 + 2], acc[g2 * 4 + 3]);
        *(u32x2*)(lvT + co * 128 + (tl ^ ((co & 15) << 2))) = pk;
      }
    } else {
      float bias = tsr ? bk[co] : bq[co];
      float scl = tsr ? 1.f : SCLQ;
      short* dst = tsr ? kg : qg;
#pragma unroll
      for (int reg = 0; reg < 16; ++reg) {
        int trow = mt * 32 + (reg & 3) + 8 * (reg >> 2) + 4 * hl;
        dst[((size_t)bn * TT + (t0 + trow)) * 64 + co] = f2bf((acc[reg] + bias) * scl);
      }
    }
  }
  __syncthreads();
  // coalesced copy-out: vgT[bn][co][t0 + t]
#pragma unroll
  for (int i = 0; i < 8; ++i) {
    int chunk = tid + 256 * i;          // 2048 chunks of 4 shorts
    int co = chunk >> 5, tc = chunk & 31;
    s16x4 v4 = *(const s16x4*)(lvT + co * 128 + ((tc * 4) ^ ((co & 15) << 2)));
    *(s16x4*)(vgT + ((size_t)bn * 64 + co) * TT + t0 + tc * 4) = v4;
  }
}

// ---------------------------------------------------------------------------
// Kernel 2: attention (round-5 structure, proven).  Grid 1024 = (bn,h,qq);
// 4 waves, 1 mt/wave.  One-pass no-max softmax.  Native v_exp_f32 via
// __builtin_amdgcn_exp2f, SHIELDED by a compiler-emitted v_max so the
// inline-asm cvtpk never directly consumes a TRANS-class def (the r6-r8
// corruption signature).  Explicit fp32 denominator (r5-proven).
// P in registers: cvt_pk + v_permlane32_swap_b32 -> 32x32x16 A-frags.
// ---------------------------------------------------------------------------
__global__ __launch_bounds__(256, 4) void k_attn(const short* __restrict__ qg,
                                                 const short* __restrict__ kg,
                                                 const short* __restrict__ vgT,
                                                 short* __restrict__ ag) {
  __shared__ __align__(16) short Kl[512 * 16];   // frag-major: tile nt at nt*512, lane*8
  __shared__ float Sums[4][32];
  const int tid = threadIdx.x;
  // bijective XCD swizzle: all 16 (h,qq) blocks of one bn land on one XCD
  const int b = (blockIdx.x & 7) * 128 + (blockIdx.x >> 3);
  const int bn = b >> 4, h = (b >> 2) & 3, qq = b & 3;
  const int lane = tid & 63, w = tid >> 6;
  const int r = lane & 31, hl = lane >> 5;

  // stage K slice (512 x 16) into fragment-major LDS
  const short* kslice = kg + (size_t)bn * TT * CC + h * 16;
  for (int s = tid; s < 1024; s += 256) {
    int row = s >> 1, hh = s & 1;
    s16x8 kv = *(const s16x8*)(kslice + (size_t)row * CC + hh * 8);
    *(s16x8*)(Kl + (row >> 5) * 512 + (row & 31) * 8 + hh * 256) = kv;
  }

  const int mt = qq * 4 + w;
  s16x8 qf = *(const s16x8*)(qg + ((size_t)bn * TT + mt * 32 + r) * CC + h * 16 + hl * 8);
  // per-lane V channel row (r>=16 duplicates r-16; those output cols discarded)
  const short* vb = vgT + ((size_t)bn * 64 + h * 16 + (r & 15)) * TT;

  __syncthreads();

  f32x16 z;
#pragma unroll
  for (int i = 0; i < 16; ++i) z[i] = 0.f;
  float sm0 = 0.f, sm1 = 0.f, sm2 = 0.f, sm3 = 0.f;
  f32x16 o;
#pragma unroll
  for (int i = 0; i < 16; ++i) o[i] = 0.f;

#pragma unroll
  for (int nt = 0; nt < 16; ++nt) {
    s16x8 kf = *(const s16x8*)(Kl + nt * 512 + lane * 8);
    f32x16 s = __builtin_amdgcn_mfma_f32_32x32x16_bf16(kf, qf, z, 0, 0, 0);
    float p[16];
#pragma unroll
    for (int i = 0; i < 16; ++i)
      p[i] = fmaxf(__builtin_amdgcn_exp2f(s[i]), 0.f);  // v_max shields asm consumer
#pragma unroll
    for (int i = 0; i < 4; ++i) {
      sm0 += p[4 * i + 0]; sm1 += p[4 * i + 1];
      sm2 += p[4 * i + 2]; sm3 += p[4 * i + 3];
    }
    unsigned pk[8];
#pragma unroll
    for (int m = 0; m < 8; ++m) pk[m] = cvtpk(p[2 * m], p[2 * m + 1]);
#pragma unroll
    for (int s2 = 0; s2 < 2; ++s2) {
      unsigned a0 = pk[4 * s2 + 0], b0 = pk[4 * s2 + 2];
      unsigned a1 = pk[4 * s2 + 1], b1 = pk[4 * s2 + 3];
      asm("v_permlane32_swap_b32 %0, %1" : "+v"(a0), "+v"(b0));
      asm("v_permlane32_swap_b32 %0, %1" : "+v"(a1), "+v"(b1));
      u32x4 fw; fw[0] = a0; fw[1] = a1; fw[2] = b0; fw[3] = b1;
      s16x8 fr = __builtin_bit_cast(s16x8, fw);
      s16x8 vf = *(const s16x8*)(vb + nt * 32 + s2 * 16 + hl * 8);
      o = __builtin_amdgcn_mfma_f32_32x32x16_bf16(fr, vf, o, 0, 0, 0);
    }
  }
  float sum = (sm0 + sm1) + (sm2 + sm3);
  sum += __shfl_xor(sum, 32);
  Sums[w][r] = sum;
  if (r < 16) {
#pragma unroll
    for (int reg = 0; reg < 16; ++reg) {
      int qlocal = (reg & 3) + 8 * (reg >> 2) + 4 * hl;
      float inv = __builtin_amdgcn_rcpf(Sums[w][qlocal]);
      int q = mt * 32 + qlocal;
      ag[((size_t)bn * TT + q) * CC + h * 16 + r] = f2bf(o[reg] * inv);
    }
  }
}

// ---------------------------------------------------------------------------
// Kernel 3: final linear out = attn @ Wf^T + bf (fp32 out)
// ---------------------------------------------------------------------------
__global__ __launch_bounds__(256) void k_out(const short* __restrict__ ag,
                                             const short* __restrict__ wfb,
                                             const float* __restrict__ bfv,
                                             float* __restrict__ out) {
  __shared__ __align__(16) short la[128 * 64];
  const int tid = threadIdx.x;
  const int bn = blockIdx.x >> 2, ttile = blockIdx.x & 3;
  const int t0 = ttile * 128;
  for (int s = tid; s < 128 * 8; s += 256) {
    int row = s >> 3, c8 = s & 7;
    s16x8 v = *(const s16x8*)(ag + ((size_t)bn * TT + t0 + row) * 64 + c8 * 8);
    int byte = row * 128 + ((c8 * 16) ^ ((row & 7) << 4));
    *(s16x8*)((char*)la + byte) = v;
  }
  __syncthreads();
  const int lane = tid & 63, w = tid >> 6;
  const int r = lane & 31, hl = lane >> 5;
  for (int job = w; job < 8; job += 4) {
    int mt = job >> 1, nt = job & 1;
    f32x16 acc;
#pragma unroll
    for (int i = 0; i < 16; ++i) acc[i] = 0.f;
#pragma unroll
    for (int c4 = 0; c4 < 4; ++c4) {
      int lrow = mt * 32 + r;
      int abyte = lrow * 128 + (((c4 * 16 + hl * 8) * 2) ^ ((lrow & 7) << 4));
      s16x8 af = *(const s16x8*)((const char*)la + abyte);
      s16x8 bfr = *(const s16x8*)(wfb + (nt * 32 + r) * 64 + c4 * 16 + hl * 8);
      acc = __builtin_amdgcn_mfma_f32_32x32x16_bf16(af, bfr, acc, 0, 0, 0);
    }
    int co = nt * 32 + r;
    float bias = bfv[co];
#pragma unroll
    for (int reg = 0; reg < 16; ++reg) {
      int trow = mt * 32 + (reg & 3) + 8 * (reg >> 2) + 4 * hl;
      out[((size_t)bn * TT + t0 + trow) * 64 + co] = acc[reg] + bias;
    }
  }
}

// ---------------------------------------------------------------------------
extern "C" void kernel_launch(void* const* d_in, const int* in_sizes, int n_in,
                              void* d_out, int out_size, void* d_ws, size_t ws_size,
                              hipStream_t stream) {
  const float* values = (const float*)d_in[0];
  const float* keys = (const float*)d_in[1];
  const float* query = (const float*)d_in[2];
  const float* Wq = (const float*)d_in[3];
  const float* bq = (const float*)d_in[4];
  const float* Wk = (const float*)d_in[5];
  const float* bk = (const float*)d_in[6];
  const float* Wv = (const float*)d_in[7];
  const float* Wf = (const float*)d_in[8];
  const float* bfv = (const float*)d_in[9];
  float* out = (float*)d_out;

  char* ws = (char*)d_ws;
  short* wsw = (short*)ws;                              // 64 KiB weights
  short* qg = (short*)(ws + (1 << 16));                 // 4 MiB each
  short* kg = (short*)(ws + (1 << 16) + (1 << 22));
  short* vgT = (short*)(ws + (1 << 16) + 2 * (1 << 22));
  short* ag = (short*)(ws + (1 << 16) + 3 * (size_t)(1 << 22));

  hipLaunchKernelGGL(k_prep, dim3(128), dim3(256), 0, stream, Wq, Wk, Wv, Wf, wsw);
  hipLaunchKernelGGL(k_qkv, dim3(256), dim3(256), 0, stream,
                     values, keys, query, bq, bk, wsw, qg, kg, vgT);
  hipLaunchKernelGGL(k_attn, dim3(1024), dim3(256), 0, stream, qg, kg, vgT, ag);
  hipLaunchKernelGGL(k_out, dim3(256), dim3(256), 0, stream, ag, wsw + 28672, bfv, out);
}